// Round 1
// baseline (252.653 us; speedup 1.0000x reference)
//
#include <hip/hip_runtime.h>
#include <hip/hip_bf16.h>

#define NB 32768
#define ND 512
#define NS 128
#define NE 8
#define TM 64
#define NTILES (NB / TM)  // 512

typedef __attribute__((ext_vector_type(8))) short bf16x8;
typedef __attribute__((ext_vector_type(4))) float f32x4;

__device__ __forceinline__ unsigned short f2b(float f) {
  union { __hip_bfloat16 h; unsigned short u; } cv;
  cv.h = __float2bfloat16(f);
  return cv.u;
}

__global__ void zero_counts_k(int* counts) {
  if (threadIdx.x < NE) counts[threadIdx.x] = 0;
}

__global__ void bin_rows_k(const int* __restrict__ yidx, int* __restrict__ counts,
                           int* __restrict__ bucket) {
  int b = blockIdx.x * blockDim.x + threadIdx.x;
  if (b < NB) {
    int e = yidx[b];
    int p = atomicAdd(&counts[e], 1);
    bucket[e * NB + p] = b;
  }
}

// [R][C] f32 -> [C][R] bf16 per matrix; grid = nmat*(R/32)*(C/32), 256 thr
__global__ void transpose_cvt_k(const float* __restrict__ in,
                                unsigned short* __restrict__ out, int R, int C) {
  __shared__ float lt[32][33];
  int tpm = (R >> 5) * (C >> 5);
  int mat = blockIdx.x / tpm;
  int rem = blockIdx.x % tpm;
  int tcn = C >> 5;
  int tr = rem / tcn, tc = rem % tcn;
  const float* mi = in + (size_t)mat * R * C;
  unsigned short* mo = out + (size_t)mat * R * C;
  int r = threadIdx.x >> 5, c = threadIdx.x & 31;
#pragma unroll
  for (int i = 0; i < 4; ++i) {
    int rr = r + i * 8;
    lt[rr][c] = mi[(size_t)(tr * 32 + rr) * C + tc * 32 + c];
  }
  __syncthreads();
#pragma unroll
  for (int i = 0; i < 4; ++i) {
    int rr = r + i * 8;
    mo[(size_t)(tc * 32 + rr) * R + tr * 32 + c] = f2b(lt[c][rr]);
  }
}

// One block = 64 rows of one expert. 256 threads = 4 waves, wave owns 16 rows.
// Stage1: H[64][128] = relu(relu(X)@W1 + b1), K=512 chunked by 64.
// Stage2: out = x + (H@W2 + b2)*z, N=512 chunked by 128.
__launch_bounds__(256)
__global__ void moe_k(const float* __restrict__ x, const float* __restrict__ z,
                      const float* __restrict__ b1, const float* __restrict__ b2,
                      const unsigned short* __restrict__ w1t,
                      const unsigned short* __restrict__ w2t,
                      const int* __restrict__ counts, const int* __restrict__ bucket,
                      float* __restrict__ out) {
  // pads: XT stride 72 (144B = 4 banks mod 32), WT/HT stride 136 (272B = 4 banks mod 32)
  __shared__ unsigned short XT[TM][72];
  __shared__ unsigned short WT[128][136];
  __shared__ unsigned short HT[TM][136];
  __shared__ int rowid[TM];
  __shared__ float zrow[TM];

  int e = blockIdx.x / NTILES;
  int t = blockIdx.x % NTILES;
  int cnt = counts[e];
  if (t * TM >= cnt) return;
  int m = min(TM, cnt - t * TM);
  int tid = threadIdx.x;
  int w = tid >> 6;
  int lane = tid & 63;
  int l15 = lane & 15;
  int l4 = lane >> 4;

  if (tid < TM) {
    int rid = (tid < m) ? bucket[e * NB + t * TM + tid] : -1;
    rowid[tid] = rid;
    zrow[tid] = (rid >= 0) ? z[rid] : 0.f;
  }
  __syncthreads();

  f32x4 acc[8];
#pragma unroll
  for (int i = 0; i < 8; ++i) acc[i] = (f32x4){0.f, 0.f, 0.f, 0.f};

  // ---------------- stage 1 ----------------
  for (int kc = 0; kc < ND; kc += 64) {
    {  // stage X tile [64 rows][64 k] with relu+cvt
      int row = tid >> 4;  // 0..15
      int c4 = tid & 15;
#pragma unroll
      for (int p = 0; p < 4; ++p) {
        int rr = p * 16 + row;
        int rid = rowid[rr];
        float4 v = make_float4(0.f, 0.f, 0.f, 0.f);
        if (rid >= 0) v = *(const float4*)&x[(size_t)rid * ND + kc + c4 * 4];
        ushort4 sv;
        sv.x = f2b(fmaxf(v.x, 0.f));
        sv.y = f2b(fmaxf(v.y, 0.f));
        sv.z = f2b(fmaxf(v.z, 0.f));
        sv.w = f2b(fmaxf(v.w, 0.f));
        *(ushort4*)&XT[rr][c4 * 4] = sv;
      }
    }
    {  // stage W1T tile [128 s][64 k]
      int n = tid >> 3;  // 0..31
      int k8 = tid & 7;
#pragma unroll
      for (int p = 0; p < 4; ++p) {
        int nn = p * 32 + n;
        uint4 v = *(const uint4*)&w1t[((size_t)e * NS + nn) * ND + kc + k8 * 8];
        *(uint4*)&WT[nn][k8 * 8] = v;
      }
    }
    __syncthreads();
    bf16x8 a0 = *(const bf16x8*)&XT[w * 16 + l15][l4 * 8];
    bf16x8 a1 = *(const bf16x8*)&XT[w * 16 + l15][32 + l4 * 8];
#pragma unroll
    for (int nt = 0; nt < 8; ++nt) {
      bf16x8 bl0 = *(const bf16x8*)&WT[nt * 16 + l15][l4 * 8];
      acc[nt] = __builtin_amdgcn_mfma_f32_16x16x32_bf16(a0, bl0, acc[nt], 0, 0, 0);
      bf16x8 bl1 = *(const bf16x8*)&WT[nt * 16 + l15][32 + l4 * 8];
      acc[nt] = __builtin_amdgcn_mfma_f32_16x16x32_bf16(a1, bl1, acc[nt], 0, 0, 0);
    }
    __syncthreads();
  }

  // H = relu(acc + b1) -> HT (bf16)
#pragma unroll
  for (int nt = 0; nt < 8; ++nt) {
    int s = nt * 16 + l15;
    float bias = b1[e * NS + s];
#pragma unroll
    for (int r = 0; r < 4; ++r) {
      int lrow = w * 16 + l4 * 4 + r;
      HT[lrow][s] = f2b(fmaxf(acc[nt][r] + bias, 0.f));
    }
  }
  __syncthreads();

  bf16x8 ha[4];
#pragma unroll
  for (int kk = 0; kk < 4; ++kk)
    ha[kk] = *(const bf16x8*)&HT[w * 16 + l15][kk * 32 + l4 * 8];

  // ---------------- stage 2 ----------------
  for (int nc = 0; nc < 4; ++nc) {
    {  // stage W2T tile [128 d][128 s]
      int n = tid >> 4;   // 0..15
      int k8 = tid & 15;  // 0..15
#pragma unroll
      for (int p = 0; p < 8; ++p) {
        int nn = p * 16 + n;
        uint4 v = *(const uint4*)&w2t[((size_t)e * ND + nc * 128 + nn) * NS + k8 * 8];
        *(uint4*)&WT[nn][k8 * 8] = v;
      }
    }
    __syncthreads();
    f32x4 acc2[8];
#pragma unroll
    for (int i = 0; i < 8; ++i) acc2[i] = (f32x4){0.f, 0.f, 0.f, 0.f};
#pragma unroll
    for (int nt = 0; nt < 8; ++nt) {
#pragma unroll
      for (int kk = 0; kk < 4; ++kk) {
        bf16x8 bfr = *(const bf16x8*)&WT[nt * 16 + l15][kk * 32 + l4 * 8];
        acc2[nt] = __builtin_amdgcn_mfma_f32_16x16x32_bf16(ha[kk], bfr, acc2[nt], 0, 0, 0);
      }
    }
    // fused epilogue: out = x + (acc2 + b2)*z
#pragma unroll
    for (int nt = 0; nt < 8; ++nt) {
      int d = nc * 128 + nt * 16 + l15;
      float bias = b2[e * ND + d];
#pragma unroll
      for (int r = 0; r < 4; ++r) {
        int lrow = w * 16 + l4 * 4 + r;
        int rid = rowid[lrow];
        if (rid >= 0) {
          size_t off = (size_t)rid * ND + d;
          out[off] = x[off] + (acc2[nt][r] + bias) * zrow[lrow];
        }
      }
    }
    __syncthreads();
  }
}

extern "C" void kernel_launch(void* const* d_in, const int* in_sizes, int n_in,
                              void* d_out, int out_size, void* d_ws, size_t ws_size,
                              hipStream_t stream) {
  const float* x = (const float*)d_in[0];
  const int* yidx = (const int*)d_in[1];
  // d_in[2] = y_hard (unused by reference)
  const float* z = (const float*)d_in[3];
  const float* W1 = (const float*)d_in[4];
  const float* b1 = (const float*)d_in[5];
  const float* W2 = (const float*)d_in[6];
  const float* b2 = (const float*)d_in[7];
  float* out = (float*)d_out;

  char* ws = (char*)d_ws;
  int* counts = (int*)ws;                                    // 8 ints (pad 256B)
  int* bucket = (int*)(ws + 256);                            // E*B ints = 1 MB
  unsigned short* w1t = (unsigned short*)(ws + 256 + (size_t)NE * NB * 4);         // 1 MB
  unsigned short* w2t = (unsigned short*)(ws + 256 + (size_t)NE * NB * 4 +
                                          (size_t)NE * ND * NS * 2);               // 1 MB

  zero_counts_k<<<1, 64, 0, stream>>>(counts);
  bin_rows_k<<<NB / 256, 256, 0, stream>>>(yidx, counts, bucket);
  // W1 [E][D][S] -> w1t [E][S][D]
  transpose_cvt_k<<<NE * (ND / 32) * (NS / 32), 256, 0, stream>>>(W1, w1t, ND, NS);
  // W2 [E][S][D] -> w2t [E][D][S]
  transpose_cvt_k<<<NE * (NS / 32) * (ND / 32), 256, 0, stream>>>(W2, w2t, NS, ND);
  moe_k<<<NE * NTILES, 256, 0, stream>>>(x, z, b1, b2, w1t, w2t, counts, bucket, out);
}

// Round 2
// 166.088 us; speedup vs baseline: 1.5212x; 1.5212x over previous
//
#include <hip/hip_runtime.h>
#include <hip/hip_bf16.h>

#define NB 32768
#define ND 512
#define NS 128
#define NE 8
#define TM 64
#define NTILES (NB / TM)  // 512

typedef __attribute__((ext_vector_type(8))) short bf16x8;
typedef __attribute__((ext_vector_type(4))) float f32x4;

__device__ __forceinline__ unsigned short f2b(float f) {
  union { __hip_bfloat16 h; unsigned short u; } cv;
  cv.h = __float2bfloat16(f);
  return cv.u;
}

// lgkm-only barrier: does NOT drain vmcnt, so global loads pipeline across it.
__device__ __forceinline__ void barrier_lgkm() {
  asm volatile("s_waitcnt lgkmcnt(0)\n\ts_barrier" ::: "memory");
}

__global__ void zero_counts_k(int* counts) {
  if (threadIdx.x < NE) counts[threadIdx.x] = 0;
}

// 1024 threads/block: LDS histogram -> 8 global atomics per block.
__global__ void bin_rows_k(const int* __restrict__ yidx, int* __restrict__ counts,
                           int* __restrict__ bucket) {
  __shared__ int lcnt[NE];
  __shared__ int lbase[NE];
  int tid = threadIdx.x;
  if (tid < NE) lcnt[tid] = 0;
  __syncthreads();
  int b = blockIdx.x * blockDim.x + tid;
  int e = yidx[b];
  int pos = atomicAdd(&lcnt[e], 1);
  __syncthreads();
  if (tid < NE) lbase[tid] = atomicAdd(&counts[tid], lcnt[tid]);
  __syncthreads();
  bucket[e * NB + lbase[e] + pos] = b;
}

// [R][C] f32 -> [C][R] bf16 per matrix; grid = nmat*(R/32)*(C/32), 256 thr
__global__ void transpose_cvt_k(const float* __restrict__ in,
                                unsigned short* __restrict__ out, int R, int C) {
  __shared__ float lt[32][33];
  int tpm = (R >> 5) * (C >> 5);
  int mat = blockIdx.x / tpm;
  int rem = blockIdx.x % tpm;
  int tcn = C >> 5;
  int tr = rem / tcn, tc = rem % tcn;
  const float* mi = in + (size_t)mat * R * C;
  unsigned short* mo = out + (size_t)mat * R * C;
  int r = threadIdx.x >> 5, c = threadIdx.x & 31;
#pragma unroll
  for (int i = 0; i < 4; ++i) {
    int rr = r + i * 8;
    lt[rr][c] = mi[(size_t)(tr * 32 + rr) * C + tc * 32 + c];
  }
  __syncthreads();
#pragma unroll
  for (int i = 0; i < 4; ++i) {
    int rr = r + i * 8;
    mo[(size_t)(tc * 32 + rr) * R + tr * 32 + c] = f2b(lt[c][rr]);
  }
}

// One block = 64 rows of one expert. 256 threads = 4 waves, wave owns 16 rows.
// W fragments read directly from global (L2-resident, identical across blocks).
// LDS: double-buffered X tile unioned with H tile (~19 KB) -> 4 blocks/CU.
__launch_bounds__(256, 4)
__global__ void moe_k(const float* __restrict__ x, const float* __restrict__ z,
                      const float* __restrict__ b1, const float* __restrict__ b2,
                      const unsigned short* __restrict__ w1t,
                      const unsigned short* __restrict__ w2t,
                      const int* __restrict__ counts, const int* __restrict__ bucket,
                      float* __restrict__ out) {
  __shared__ union {
    unsigned short xt[2][TM][72];   // 18432 B
    unsigned short ht[TM][136];     // 17408 B
  } sm;
  __shared__ int rowid[TM];
  __shared__ float zrow[TM];

  int e = blockIdx.x / NTILES;
  int t = blockIdx.x % NTILES;
  int cnt = counts[e];
  if (t * TM >= cnt) return;  // uniform early exit, before any barrier
  int m = min(TM, cnt - t * TM);
  int tid = threadIdx.x;
  int w = tid >> 6, lane = tid & 63;
  int l15 = lane & 15, l4 = lane >> 4;

  if (tid < TM) {
    int rid = (tid < m) ? bucket[e * NB + t * TM + tid] : -1;
    rowid[tid] = rid;
    zrow[tid] = (rid >= 0) ? z[rid] : 0.f;
  }
  barrier_lgkm();

  // staging roles: thread -> 4 rows (p*16 + srow), 16 B of k each
  int srow = tid >> 4, sc4 = tid & 15;
  int srid[4];
#pragma unroll
  for (int p = 0; p < 4; ++p) srid[p] = rowid[p * 16 + srow];

  float4 xr[4];
#pragma unroll
  for (int p = 0; p < 4; ++p) {
    xr[p] = make_float4(0.f, 0.f, 0.f, 0.f);
    if (srid[p] >= 0) xr[p] = *(const float4*)&x[(size_t)srid[p] * ND + sc4 * 4];
  }
#pragma unroll
  for (int p = 0; p < 4; ++p) {
    ushort4 sv;
    sv.x = f2b(fmaxf(xr[p].x, 0.f));
    sv.y = f2b(fmaxf(xr[p].y, 0.f));
    sv.z = f2b(fmaxf(xr[p].z, 0.f));
    sv.w = f2b(fmaxf(xr[p].w, 0.f));
    *(ushort4*)&sm.xt[0][p * 16 + srow][sc4 * 4] = sv;
  }
  barrier_lgkm();

  f32x4 acc[8];
#pragma unroll
  for (int i = 0; i < 8; ++i) acc[i] = (f32x4){0.f, 0.f, 0.f, 0.f};

  const unsigned short* w1e = w1t + (size_t)e * NS * ND;

  // ---------------- stage 1: H = relu(relu(X) @ W1 + b1) ----------------
#pragma unroll
  for (int c = 0; c < 8; ++c) {
    int kc = c * 64;
    if (c < 7) {  // issue next X chunk early (T14: hide HBM under MFMAs)
#pragma unroll
      for (int p = 0; p < 4; ++p) {
        xr[p] = make_float4(0.f, 0.f, 0.f, 0.f);
        if (srid[p] >= 0)
          xr[p] = *(const float4*)&x[(size_t)srid[p] * ND + kc + 64 + sc4 * 4];
      }
    }
    bf16x8 a0 = *(const bf16x8*)&sm.xt[c & 1][w * 16 + l15][l4 * 8];
    bf16x8 a1 = *(const bf16x8*)&sm.xt[c & 1][w * 16 + l15][32 + l4 * 8];
#pragma unroll
    for (int nt = 0; nt < 8; ++nt) {
      const unsigned short* wr = &w1e[(size_t)(nt * 16 + l15) * ND + kc + l4 * 8];
      bf16x8 bf0 = *(const bf16x8*)wr;
      bf16x8 bf1 = *(const bf16x8*)(wr + 32);
      acc[nt] = __builtin_amdgcn_mfma_f32_16x16x32_bf16(a0, bf0, acc[nt], 0, 0, 0);
      acc[nt] = __builtin_amdgcn_mfma_f32_16x16x32_bf16(a1, bf1, acc[nt], 0, 0, 0);
    }
    if (c < 7) {  // write-late into the other buffer
#pragma unroll
      for (int p = 0; p < 4; ++p) {
        ushort4 sv;
        sv.x = f2b(fmaxf(xr[p].x, 0.f));
        sv.y = f2b(fmaxf(xr[p].y, 0.f));
        sv.z = f2b(fmaxf(xr[p].z, 0.f));
        sv.w = f2b(fmaxf(xr[p].w, 0.f));
        *(ushort4*)&sm.xt[(c & 1) ^ 1][p * 16 + srow][sc4 * 4] = sv;
      }
    }
    barrier_lgkm();
  }

  // H -> LDS (bf16), rows are wave-private so only lgkm ordering needed,
  // but the union overwrite of xt needs the barrier above (already done).
#pragma unroll
  for (int nt = 0; nt < 8; ++nt) {
    int s = nt * 16 + l15;
    float bias = b1[e * NS + s];
#pragma unroll
    for (int r = 0; r < 4; ++r)
      sm.ht[w * 16 + l4 * 4 + r][s] = f2b(fmaxf(acc[nt][r] + bias, 0.f));
  }
  asm volatile("s_waitcnt lgkmcnt(0)" ::: "memory");  // own rows only

  bf16x8 ha[4];
#pragma unroll
  for (int kk = 0; kk < 4; ++kk)
    ha[kk] = *(const bf16x8*)&sm.ht[w * 16 + l15][kk * 32 + l4 * 8];

  int orow[4];
  float zr4[4];
#pragma unroll
  for (int r = 0; r < 4; ++r) {
    int lrow = w * 16 + l4 * 4 + r;
    orow[r] = rowid[lrow];
    zr4[r] = zrow[lrow];
  }

  // ---------------- stage 2: out = x + (H @ W2 + b2) * z  (no barriers) ----
  const unsigned short* w2e = w2t + (size_t)e * ND * NS;
#pragma unroll 1
  for (int nc = 0; nc < 4; ++nc) {
    f32x4 acc2[8];
#pragma unroll
    for (int i = 0; i < 8; ++i) acc2[i] = (f32x4){0.f, 0.f, 0.f, 0.f};
#pragma unroll
    for (int nt = 0; nt < 8; ++nt) {
      const unsigned short* wr = &w2e[(size_t)(nc * 128 + nt * 16 + l15) * NS + l4 * 8];
#pragma unroll
      for (int kk = 0; kk < 4; ++kk) {
        bf16x8 bfr = *(const bf16x8*)(wr + kk * 32);
        acc2[nt] = __builtin_amdgcn_mfma_f32_16x16x32_bf16(ha[kk], bfr, acc2[nt], 0, 0, 0);
      }
    }
#pragma unroll
    for (int nt = 0; nt < 8; ++nt) {
      int d = nc * 128 + nt * 16 + l15;
      float bias = b2[e * ND + d];
#pragma unroll
      for (int r = 0; r < 4; ++r) {
        if (orow[r] >= 0) {
          size_t off = (size_t)orow[r] * ND + d;
          out[off] = x[off] + (acc2[nt][r] + bias) * zr4[r];
        }
      }
    }
  }
}

extern "C" void kernel_launch(void* const* d_in, const int* in_sizes, int n_in,
                              void* d_out, int out_size, void* d_ws, size_t ws_size,
                              hipStream_t stream) {
  const float* x = (const float*)d_in[0];
  const int* yidx = (const int*)d_in[1];
  // d_in[2] = y_hard (unused by reference)
  const float* z = (const float*)d_in[3];
  const float* W1 = (const float*)d_in[4];
  const float* b1 = (const float*)d_in[5];
  const float* W2 = (const float*)d_in[6];
  const float* b2 = (const float*)d_in[7];
  float* out = (float*)d_out;

  char* ws = (char*)d_ws;
  int* counts = (int*)ws;                                              // 256 B
  int* bucket = (int*)(ws + 256);                                      // 1 MB
  unsigned short* w1t = (unsigned short*)(ws + 256 + (size_t)NE * NB * 4);
  unsigned short* w2t = (unsigned short*)(ws + 256 + (size_t)NE * NB * 4 +
                                          (size_t)NE * ND * NS * 2);

  zero_counts_k<<<1, 64, 0, stream>>>(counts);
  bin_rows_k<<<NB / 1024, 1024, 0, stream>>>(yidx, counts, bucket);
  // W1 [E][D][S] -> w1t [E][S][D]
  transpose_cvt_k<<<NE * (ND / 32) * (NS / 32), 256, 0, stream>>>(W1, w1t, ND, NS);
  // W2 [E][S][D] -> w2t [E][D][S]
  transpose_cvt_k<<<NE * (NS / 32) * (ND / 32), 256, 0, stream>>>(W2, w2t, NS, ND);
  moe_k<<<NE * NTILES, 256, 0, stream>>>(x, z, b1, b2, w1t, w2t, counts, bucket, out);
}

// Round 3
// 157.313 us; speedup vs baseline: 1.6060x; 1.0558x over previous
//
#include <hip/hip_runtime.h>
#include <hip/hip_bf16.h>

#define NB 32768
#define ND 512
#define NS 128
#define NE 8
#define TM 16
#define NTILES (NB / TM)  // 2048

typedef __attribute__((ext_vector_type(8))) short bf16x8;
typedef __attribute__((ext_vector_type(8))) unsigned short u16x8;
typedef __attribute__((ext_vector_type(4))) float f32x4;

__device__ __forceinline__ unsigned short f2b(float f) {
  union { __hip_bfloat16 h; unsigned short u; } cv;
  cv.h = __float2bfloat16(f);
  return cv.u;
}

__global__ void zero_counts_k(int* counts) {
  if (threadIdx.x < NE) counts[threadIdx.x] = 0;
}

// 1024 threads/block: LDS histogram -> 8 global atomics per block.
__global__ void bin_rows_k(const int* __restrict__ yidx, int* __restrict__ counts,
                           int* __restrict__ bucket) {
  __shared__ int lcnt[NE];
  __shared__ int lbase[NE];
  int tid = threadIdx.x;
  if (tid < NE) lcnt[tid] = 0;
  __syncthreads();
  int b = blockIdx.x * blockDim.x + tid;
  int e = yidx[b];
  int pos = atomicAdd(&lcnt[e], 1);
  __syncthreads();
  if (tid < NE) lbase[tid] = atomicAdd(&counts[tid], lcnt[tid]);
  __syncthreads();
  bucket[e * NB + lbase[e] + pos] = b;
}

// [R][C] f32 -> [C][R] bf16 per matrix; grid = nmat*(R/32)*(C/32), 256 thr
__global__ void transpose_cvt_k(const float* __restrict__ in,
                                unsigned short* __restrict__ out, int R, int C) {
  __shared__ float lt[32][33];
  int tpm = (R >> 5) * (C >> 5);
  int mat = blockIdx.x / tpm;
  int rem = blockIdx.x % tpm;
  int tcn = C >> 5;
  int tr = rem / tcn, tc = rem % tcn;
  const float* mi = in + (size_t)mat * R * C;
  unsigned short* mo = out + (size_t)mat * R * C;
  int r = threadIdx.x >> 5, c = threadIdx.x & 31;
#pragma unroll
  for (int i = 0; i < 4; ++i) {
    int rr = r + i * 8;
    lt[rr][c] = mi[(size_t)(tr * 32 + rr) * C + tc * 32 + c];
  }
  __syncthreads();
#pragma unroll
  for (int i = 0; i < 4; ++i) {
    int rr = r + i * 8;
    mo[(size_t)(tc * 32 + rr) * R + tr * 32 + c] = f2b(lt[c][rr]);
  }
}

// One block = 16 rows of one expert; 4 waves split COLUMNS.
// Stage1: wave w computes H[16][w*32..w*32+32), K=512 unrolled, no barriers.
// Stage2: wave w computes out cols [w*128..w*128+128), no barriers.
// X tile staged once (relu+cvt) into LDS; W frags direct from L2.
__launch_bounds__(256, 4)
__global__ void moe_k(const float* __restrict__ x, const float* __restrict__ z,
                      const float* __restrict__ b1, const float* __restrict__ b2,
                      const unsigned short* __restrict__ w1t,
                      const unsigned short* __restrict__ w2t,
                      const int* __restrict__ counts, const int* __restrict__ bucket,
                      float* __restrict__ out) {
  __shared__ unsigned short xt[TM][516];  // pad: 1032B row ≡ 2 banks mod 32
  __shared__ unsigned short ht[TM][132];  // pad: 264B row ≡ 2 banks mod 32
  __shared__ int rowid[TM];
  __shared__ float zrow[TM];

  int e = blockIdx.x >> 11;
  int t = blockIdx.x & (NTILES - 1);
  int cnt = counts[e];
  if (t * TM >= cnt) return;  // uniform exit before any barrier
  int m = min(TM, cnt - t * TM);
  int tid = threadIdx.x;
  int w = tid >> 6, lane = tid & 63;
  int l15 = lane & 15, l4 = lane >> 4;

  if (tid < TM) {
    int rid = (tid < m) ? bucket[e * NB + t * TM + tid] : -1;
    rowid[tid] = rid;
    zrow[tid] = (rid >= 0) ? z[rid] : 0.f;
  }

  // ---- stage X tile: thread -> row (tid&15), 32-elem col chunk (tid>>4) ----
  {
    int srow = tid & 15;
    int scc = tid >> 4;
    int srid = (srow < m) ? bucket[e * NB + t * TM + srow] : -1;
    const float* xrow = x + (size_t)srid * ND + scc * 32;
    float4 v[8];
#pragma unroll
    for (int j = 0; j < 8; ++j)
      v[j] = (srid >= 0) ? *(const float4*)(xrow + j * 4)
                         : make_float4(0.f, 0.f, 0.f, 0.f);
#pragma unroll
    for (int j = 0; j < 4; ++j) {
      u16x8 pk;
      pk[0] = f2b(fmaxf(v[2 * j].x, 0.f));
      pk[1] = f2b(fmaxf(v[2 * j].y, 0.f));
      pk[2] = f2b(fmaxf(v[2 * j].z, 0.f));
      pk[3] = f2b(fmaxf(v[2 * j].w, 0.f));
      pk[4] = f2b(fmaxf(v[2 * j + 1].x, 0.f));
      pk[5] = f2b(fmaxf(v[2 * j + 1].y, 0.f));
      pk[6] = f2b(fmaxf(v[2 * j + 1].z, 0.f));
      pk[7] = f2b(fmaxf(v[2 * j + 1].w, 0.f));
      *(u16x8*)&xt[srow][scc * 32 + j * 8] = pk;
    }
  }
  __syncthreads();

  // ---------------- stage 1 (barrier-free, fully unrolled) ----------------
  const unsigned short* w1e = w1t + (size_t)e * NS * ND;
  const unsigned short* w1p0 = w1e + (size_t)(w * 32 + l15) * ND + l4 * 8;
  const unsigned short* w1p1 = w1p0 + (size_t)16 * ND;
  f32x4 acc0 = (f32x4){0.f, 0.f, 0.f, 0.f};
  f32x4 acc1 = (f32x4){0.f, 0.f, 0.f, 0.f};
#pragma unroll
  for (int c = 0; c < 8; ++c) {
    bf16x8 a0 = *(const bf16x8*)&xt[l15][c * 64 + l4 * 8];
    bf16x8 a1 = *(const bf16x8*)&xt[l15][c * 64 + 32 + l4 * 8];
    bf16x8 b00 = *(const bf16x8*)(w1p0 + c * 64);
    bf16x8 b01 = *(const bf16x8*)(w1p0 + c * 64 + 32);
    bf16x8 b10 = *(const bf16x8*)(w1p1 + c * 64);
    bf16x8 b11 = *(const bf16x8*)(w1p1 + c * 64 + 32);
    acc0 = __builtin_amdgcn_mfma_f32_16x16x32_bf16(a0, b00, acc0, 0, 0, 0);
    acc0 = __builtin_amdgcn_mfma_f32_16x16x32_bf16(a1, b01, acc0, 0, 0, 0);
    acc1 = __builtin_amdgcn_mfma_f32_16x16x32_bf16(a0, b10, acc1, 0, 0, 0);
    acc1 = __builtin_amdgcn_mfma_f32_16x16x32_bf16(a1, b11, acc1, 0, 0, 0);
  }

  // H = relu(acc + b1) -> ht (bf16); wave-private columns
  {
    int s0 = w * 32 + l15;
    float bias0 = b1[e * NS + s0];
    float bias1 = b1[e * NS + s0 + 16];
#pragma unroll
    for (int r = 0; r < 4; ++r) {
      ht[l4 * 4 + r][s0] = f2b(fmaxf(acc0[r] + bias0, 0.f));
      ht[l4 * 4 + r][s0 + 16] = f2b(fmaxf(acc1[r] + bias1, 0.f));
    }
  }
  __syncthreads();

  // ---------------- stage 2 (barrier-free) ----------------
  bf16x8 ha[4];
#pragma unroll
  for (int kk = 0; kk < 4; ++kk)
    ha[kk] = *(const bf16x8*)&ht[l15][kk * 32 + l4 * 8];

  int orow[4];
  float zr4[4];
#pragma unroll
  for (int r = 0; r < 4; ++r) {
    orow[r] = rowid[l4 * 4 + r];
    zr4[r] = zrow[l4 * 4 + r];
  }

  const unsigned short* w2e = w2t + (size_t)e * ND * NS;
  const unsigned short* w2p = w2e + (size_t)(w * 128 + l15) * NS + l4 * 8;
  f32x4 acc2[8];
#pragma unroll
  for (int i = 0; i < 8; ++i) acc2[i] = (f32x4){0.f, 0.f, 0.f, 0.f};
#pragma unroll
  for (int nt = 0; nt < 8; ++nt) {
    const unsigned short* p = w2p + (size_t)nt * 16 * NS;
#pragma unroll
    for (int kk = 0; kk < 4; ++kk) {
      bf16x8 bfr = *(const bf16x8*)(p + kk * 32);
      acc2[nt] = __builtin_amdgcn_mfma_f32_16x16x32_bf16(ha[kk], bfr, acc2[nt], 0, 0, 0);
    }
  }

  // epilogue: out = x + (acc2 + b2) * z
#pragma unroll
  for (int nt = 0; nt < 8; ++nt) {
    int d = w * 128 + nt * 16 + l15;
    float bias = b2[e * ND + d];
#pragma unroll
    for (int r = 0; r < 4; ++r) {
      if (orow[r] >= 0) {
        size_t off = (size_t)orow[r] * ND + d;
        out[off] = x[off] + (acc2[nt][r] + bias) * zr4[r];
      }
    }
  }
}

extern "C" void kernel_launch(void* const* d_in, const int* in_sizes, int n_in,
                              void* d_out, int out_size, void* d_ws, size_t ws_size,
                              hipStream_t stream) {
  const float* x = (const float*)d_in[0];
  const int* yidx = (const int*)d_in[1];
  // d_in[2] = y_hard (unused by reference)
  const float* z = (const float*)d_in[3];
  const float* W1 = (const float*)d_in[4];
  const float* b1 = (const float*)d_in[5];
  const float* W2 = (const float*)d_in[6];
  const float* b2 = (const float*)d_in[7];
  float* out = (float*)d_out;

  char* ws = (char*)d_ws;
  int* counts = (int*)ws;                                              // 256 B
  int* bucket = (int*)(ws + 256);                                      // 1 MB
  unsigned short* w1t = (unsigned short*)(ws + 256 + (size_t)NE * NB * 4);
  unsigned short* w2t = (unsigned short*)(ws + 256 + (size_t)NE * NB * 4 +
                                          (size_t)NE * ND * NS * 2);

  zero_counts_k<<<1, 64, 0, stream>>>(counts);
  bin_rows_k<<<NB / 1024, 1024, 0, stream>>>(yidx, counts, bucket);
  // W1 [E][D][S] -> w1t [E][S][D]
  transpose_cvt_k<<<NE * (ND / 32) * (NS / 32), 256, 0, stream>>>(W1, w1t, ND, NS);
  // W2 [E][S][D] -> w2t [E][D][S]
  transpose_cvt_k<<<NE * (NS / 32) * (ND / 32), 256, 0, stream>>>(W2, w2t, NS, ND);
  moe_k<<<NE * NTILES, 256, 0, stream>>>(x, z, b1, b2, w1t, w2t, counts, bucket, out);
}

// Round 4
// 119.987 us; speedup vs baseline: 2.1057x; 1.3111x over previous
//
#include <hip/hip_runtime.h>
#include <hip/hip_bf16.h>

#define NB 32768
#define ND 512
#define NS 128
#define NE 8
#define TM 64
#define NT_PER_E (NB / TM)  // 512

typedef __attribute__((ext_vector_type(8))) short bf16x8;
typedef __attribute__((ext_vector_type(8))) unsigned short u16x8;
typedef __attribute__((ext_vector_type(4))) float f32x4;

__device__ __forceinline__ unsigned short f2b(float f) {
  union { __hip_bfloat16 h; unsigned short u; } cv;
  cv.h = __float2bfloat16(f);
  return cv.u;
}

__device__ __forceinline__ u16x8 relu_cvt8(float4 a, float4 b) {
  u16x8 r;
  r[0] = f2b(fmaxf(a.x, 0.f)); r[1] = f2b(fmaxf(a.y, 0.f));
  r[2] = f2b(fmaxf(a.z, 0.f)); r[3] = f2b(fmaxf(a.w, 0.f));
  r[4] = f2b(fmaxf(b.x, 0.f)); r[5] = f2b(fmaxf(b.y, 0.f));
  r[6] = f2b(fmaxf(b.z, 0.f)); r[7] = f2b(fmaxf(b.w, 0.f));
  return r;
}

// lgkm-only barrier: does NOT drain vmcnt, global loads stay in flight.
__device__ __forceinline__ void barrier_lgkm() {
  asm volatile("s_waitcnt lgkmcnt(0)\n\ts_barrier" ::: "memory");
}

__global__ void zero_counts_k(int* counts) {
  if (threadIdx.x < NE) counts[threadIdx.x] = 0;
}

__global__ void bin_rows_k(const int* __restrict__ yidx, int* __restrict__ counts,
                           int* __restrict__ bucket) {
  __shared__ int lcnt[NE];
  __shared__ int lbase[NE];
  int tid = threadIdx.x;
  if (tid < NE) lcnt[tid] = 0;
  __syncthreads();
  int b = blockIdx.x * blockDim.x + tid;
  int e = yidx[b];
  int pos = atomicAdd(&lcnt[e], 1);
  __syncthreads();
  if (tid < NE) lbase[tid] = atomicAdd(&counts[tid], lcnt[tid]);
  __syncthreads();
  bucket[e * NB + lbase[e] + pos] = b;
}

// [R][C] f32 -> [C][R] bf16 per matrix; grid = nmat*(R/32)*(C/32), 256 thr
__global__ void transpose_cvt_k(const float* __restrict__ in,
                                unsigned short* __restrict__ out, int R, int C) {
  __shared__ float lt[32][33];
  int tpm = (R >> 5) * (C >> 5);
  int mat = blockIdx.x / tpm;
  int rem = blockIdx.x % tpm;
  int tcn = C >> 5;
  int tr = rem / tcn, tc = rem % tcn;
  const float* mi = in + (size_t)mat * R * C;
  unsigned short* mo = out + (size_t)mat * R * C;
  int r = threadIdx.x >> 5, c = threadIdx.x & 31;
#pragma unroll
  for (int i = 0; i < 4; ++i) {
    int rr = r + i * 8;
    lt[rr][c] = mi[(size_t)(tr * 32 + rr) * C + tc * 32 + c];
  }
  __syncthreads();
#pragma unroll
  for (int i = 0; i < 4; ++i) {
    int rr = r + i * 8;
    mo[(size_t)(tc * 32 + rr) * R + tr * 32 + c] = f2b(lt[c][rr]);
  }
}

// Block = 64 rows of one expert, 512 threads = 8 waves (4 row-groups x 2 halves).
// All MFMA operands from LDS; weights/X chunk-staged (reg-stage, dbuf,
// issue-early/write-late). Stage1: K-chunks of 64. Stage2: N-chunks of 64.
__launch_bounds__(512, 4)
__global__ void moe_k(const float* __restrict__ x, const float* __restrict__ z,
                      const float* __restrict__ b1, const float* __restrict__ b2,
                      const unsigned short* __restrict__ w1t,
                      const unsigned short* __restrict__ w2t,
                      const int* __restrict__ counts, const int* __restrict__ bucket,
                      float* __restrict__ out) {
  __shared__ unsigned short xt[2][TM][72];   // X chunk [64 rows][64 k], pad 72
  __shared__ unsigned short wbuf[2][9216];   // W1 [128][72] or W2 [64][136]
  __shared__ unsigned short ht[TM][136];     // H [64][128], pad 136
  __shared__ int rowid[TM];
  __shared__ float zrow[TM];

  int e = blockIdx.x >> 9;
  int t = blockIdx.x & (NT_PER_E - 1);
  int cnt = counts[e];
  if (t * TM >= cnt) return;  // uniform exit before any barrier
  int m = min(TM, cnt - t * TM);
  int tid = threadIdx.x;
  int lane = tid & 63;
  int l15 = lane & 15, l4 = lane >> 4;
  int w = tid >> 6;
  int rg = w >> 1;   // row-group: rows rg*16..rg*16+15
  int nh = w & 1;    // column half

  if (tid < TM) {
    int rid = (tid < m) ? bucket[e * NB + t * TM + tid] : -1;
    rowid[tid] = rid;
    zrow[tid] = (rid >= 0) ? z[rid] : 0.f;
  }
  barrier_lgkm();

  // staging roles
  int xrow = tid >> 3, xc = (tid & 7) * 8;        // X: 8 floats/thread
  int xrid = rowid[xrow];
  const float* xsrc = x + (size_t)xrid * ND + xc;
  int w1row = tid >> 2, w1c = (tid & 3) * 16;     // W1: 16 shorts/thread
  const unsigned short* w1src =
      w1t + (size_t)e * NS * ND + (size_t)w1row * ND + w1c;
  int w2row = tid >> 3, w2c = (tid & 7) * 16;     // W2: 16 shorts/thread
  const unsigned short* w2src =
      w2t + (size_t)e * ND * NS + (size_t)w2row * NS + w2c;

  const float4 zero4 = make_float4(0.f, 0.f, 0.f, 0.f);

  // prologue: stage X chunk0 + W1 chunk0 into buffer 0
  {
    float4 xa = (xrid >= 0) ? *(const float4*)(xsrc) : zero4;
    float4 xb = (xrid >= 0) ? *(const float4*)(xsrc + 4) : zero4;
    u16x8 wa = *(const u16x8*)(w1src);
    u16x8 wb = *(const u16x8*)(w1src + 8);
    *(u16x8*)&xt[0][xrow][xc] = relu_cvt8(xa, xb);
    *(u16x8*)&wbuf[0][w1row * 72 + w1c] = wa;
    *(u16x8*)&wbuf[0][w1row * 72 + w1c + 8] = wb;
  }
  barrier_lgkm();

  f32x4 acc[4];
#pragma unroll
  for (int i = 0; i < 4; ++i) acc[i] = (f32x4){0.f, 0.f, 0.f, 0.f};

  // ---------------- stage 1: H = relu(relu(X) @ W1 + b1) ----------------
  float4 xa, xb;
  u16x8 wa, wb;
  for (int kc = 0; kc < 8; ++kc) {
    int buf = kc & 1;
    if (kc < 7) {  // issue next X + W1 chunk loads (early)
      int off = (kc + 1) * 64;
      xa = (xrid >= 0) ? *(const float4*)(xsrc + off) : zero4;
      xb = (xrid >= 0) ? *(const float4*)(xsrc + off + 4) : zero4;
      wa = *(const u16x8*)(w1src + off);
      wb = *(const u16x8*)(w1src + off + 8);
    } else {       // last iter prefetches W2 chunk 0 instead
      wa = *(const u16x8*)(w2src);
      wb = *(const u16x8*)(w2src + 8);
    }
    bf16x8 a0 = *(const bf16x8*)&xt[buf][rg * 16 + l15][l4 * 8];
    bf16x8 a1 = *(const bf16x8*)&xt[buf][rg * 16 + l15][32 + l4 * 8];
#pragma unroll
    for (int nt = 0; nt < 4; ++nt) {
      int n = nh * 64 + nt * 16 + l15;
      bf16x8 b0 = *(const bf16x8*)&wbuf[buf][n * 72 + l4 * 8];
      bf16x8 b1f = *(const bf16x8*)&wbuf[buf][n * 72 + 32 + l4 * 8];
      acc[nt] = __builtin_amdgcn_mfma_f32_16x16x32_bf16(a0, b0, acc[nt], 0, 0, 0);
      acc[nt] = __builtin_amdgcn_mfma_f32_16x16x32_bf16(a1, b1f, acc[nt], 0, 0, 0);
    }
    barrier_lgkm();
    if (kc < 7) {  // write-late into the other buffer
      *(u16x8*)&xt[buf ^ 1][xrow][xc] = relu_cvt8(xa, xb);
      *(u16x8*)&wbuf[buf ^ 1][w1row * 72 + w1c] = wa;
      *(u16x8*)&wbuf[buf ^ 1][w1row * 72 + w1c + 8] = wb;
    } else {       // W2 chunk 0 -> buffer 0
      *(u16x8*)&wbuf[0][w2row * 136 + w2c] = wa;
      *(u16x8*)&wbuf[0][w2row * 136 + w2c + 8] = wb;
    }
    barrier_lgkm();
  }

  // H = relu(acc + b1) -> ht (cross-wave shared between nh halves)
#pragma unroll
  for (int nt = 0; nt < 4; ++nt) {
    int s = nh * 64 + nt * 16 + l15;
    float bias = b1[e * NS + s];
#pragma unroll
    for (int r = 0; r < 4; ++r)
      ht[rg * 16 + l4 * 4 + r][s] = f2b(fmaxf(acc[nt][r] + bias, 0.f));
  }
  barrier_lgkm();

  bf16x8 ha[4];
#pragma unroll
  for (int kk = 0; kk < 4; ++kk)
    ha[kk] = *(const bf16x8*)&ht[rg * 16 + l15][kk * 32 + l4 * 8];

  int orow[4];
  float zr4[4];
#pragma unroll
  for (int r = 0; r < 4; ++r) {
    int lrow = rg * 16 + l4 * 4 + r;
    orow[r] = rowid[lrow];
    zr4[r] = zrow[lrow];
  }

  // ---------------- stage 2: out = x + (H @ W2 + b2) * z ----------------
  for (int nc = 0; nc < 8; ++nc) {
    int buf = nc & 1;
    if (nc < 7) {  // issue next W2 chunk loads
      int off = (nc + 1) * 64 * NS;
      wa = *(const u16x8*)(w2src + off);
      wb = *(const u16x8*)(w2src + off + 8);
    }
    f32x4 acc2[2];
    acc2[0] = (f32x4){0.f, 0.f, 0.f, 0.f};
    acc2[1] = (f32x4){0.f, 0.f, 0.f, 0.f};
#pragma unroll
    for (int nt = 0; nt < 2; ++nt) {
      int dl = nh * 32 + nt * 16 + l15;
#pragma unroll
      for (int kk = 0; kk < 4; ++kk) {
        bf16x8 bfr = *(const bf16x8*)&wbuf[buf][dl * 136 + kk * 32 + l4 * 8];
        acc2[nt] = __builtin_amdgcn_mfma_f32_16x16x32_bf16(ha[kk], bfr, acc2[nt], 0, 0, 0);
      }
    }
    // fused epilogue for these 64 columns
#pragma unroll
    for (int nt = 0; nt < 2; ++nt) {
      int d = nc * 64 + nh * 32 + nt * 16 + l15;
      float bias = b2[e * ND + d];
#pragma unroll
      for (int r = 0; r < 4; ++r) {
        if (orow[r] >= 0) {
          size_t off2 = (size_t)orow[r] * ND + d;
          out[off2] = x[off2] + (acc2[nt][r] + bias) * zr4[r];
        }
      }
    }
    if (nc < 7) {
      barrier_lgkm();
      *(u16x8*)&wbuf[buf ^ 1][w2row * 136 + w2c] = wa;
      *(u16x8*)&wbuf[buf ^ 1][w2row * 136 + w2c + 8] = wb;
      barrier_lgkm();
    }
  }
}

extern "C" void kernel_launch(void* const* d_in, const int* in_sizes, int n_in,
                              void* d_out, int out_size, void* d_ws, size_t ws_size,
                              hipStream_t stream) {
  const float* x = (const float*)d_in[0];
  const int* yidx = (const int*)d_in[1];
  // d_in[2] = y_hard (unused by reference)
  const float* z = (const float*)d_in[3];
  const float* W1 = (const float*)d_in[4];
  const float* b1 = (const float*)d_in[5];
  const float* W2 = (const float*)d_in[6];
  const float* b2 = (const float*)d_in[7];
  float* out = (float*)d_out;

  char* ws = (char*)d_ws;
  int* counts = (int*)ws;                                              // 256 B
  int* bucket = (int*)(ws + 256);                                      // 1 MB
  unsigned short* w1t = (unsigned short*)(ws + 256 + (size_t)NE * NB * 4);
  unsigned short* w2t = (unsigned short*)(ws + 256 + (size_t)NE * NB * 4 +
                                          (size_t)NE * ND * NS * 2);

  zero_counts_k<<<1, 64, 0, stream>>>(counts);
  bin_rows_k<<<NB / 1024, 1024, 0, stream>>>(yidx, counts, bucket);
  // W1 [E][D][S] -> w1t [E][S][D]
  transpose_cvt_k<<<NE * (ND / 32) * (NS / 32), 256, 0, stream>>>(W1, w1t, ND, NS);
  // W2 [E][S][D] -> w2t [E][D][S]
  transpose_cvt_k<<<NE * (NS / 32) * (ND / 32), 256, 0, stream>>>(W2, w2t, NS, ND);
  moe_k<<<NE * NT_PER_E, 512, 0, stream>>>(x, z, b1, b2, w1t, w2t, counts, bucket, out);
}